// Round 11
// baseline (240.353 us; speedup 1.0000x reference)
//
#include <hip/hip_runtime.h>
#include <math.h>

// Problem constants
#define TB 2
#define TT 31
#define TH 160
#define TW 160
#define THW (TH*TW)            // 25600
#define NPER (TB*TT*THW)       // 1,587,200
#define HCN 16
#define LSK 40                 // k1 LDS row stride

// Workspace layout (bytes). gates bf16: z-half [0,50.79MB), f-half [50.79,101.58MB).
// Gates AND h are stored TILE-MAJOR within each (channel,t) plane:
//   offset_in_plane = tile*256 + py*32 + px   (tile = (y/8)*5 + x/32, 32x8 px)
// k1 stores gates tiled (full 128B-line wave stores; k4 FETCH 142->30MB proven).
// k3 reads z/f tiled, writes h IN PLACE at the SAME address (race-free).
// k4 reads h via 9 precomputed tiled offsets. c2/c3 (standard layout, bf16)
// alias the dead f-half. Stats at the end.
#define GF_OFF_US  25395200L    // ushort offset of f-gates (2*16*31*25600)
#define C2_BYTE    50790400L    // byte offset of c2 bf16 (aliases f-gates, dead by then)
#define STATS_BYTE 101580800L

__device__ __forceinline__ float sigmoidf_(float x) {
    return __builtin_amdgcn_rcpf(1.f + __expf(-x));
}
__device__ __forceinline__ float tanhf_(float x) {
    return 2.f * __builtin_amdgcn_rcpf(1.f + __expf(-2.f * x)) - 1.f;
}
__device__ __forceinline__ unsigned short f2bf(float v) {
    unsigned int b = __float_as_uint(v);
    unsigned int r = (b + 0x7FFFu + ((b >> 16) & 1u)) >> 16;   // RNE
    return (unsigned short)r;
}
__device__ __forceinline__ float b2f(unsigned short u) {
    return __uint_as_float(((unsigned int)u) << 16);
}
// tiled uint-index of even pixel (yy, xx) within a (c,t) plane
__device__ __forceinline__ int uoff_tiled(int yy, int xx) {
    return (((yy >> 3) * 5 + (xx >> 5)) << 7) + ((yy & 7) << 4) + ((xx & 31) >> 1);
}

// ---------- kernel 1: conv1, R19 4-t groups + R20 tiled full-line stores (frozen) ----------
// grid: (8 = chalf*4 + tchunk, 100 tiles 32x8, 2 b), block 256
__global__ __launch_bounds__(256)
void k1_gates_stats(const float* __restrict__ in, const float* __restrict__ wg,
                    unsigned short* __restrict__ gout, float* __restrict__ stats) {
    __shared__ float pl[10*10*LSK];          // 10 t-planes, 10 rows x 40 (34 used)
    __shared__ float redS[4][16], redQ[4][16];

    int bx = blockIdx.x;
    int tc = bx & 3, chalf = bx >> 2;
    int tile = blockIdx.y, b = blockIdx.z;
    int ty0 = (tile / 5) * 8, tx0 = (tile % 5) * 32;
    int tid = threadIdx.x;
    int lyk = tid >> 5, lxk = tid & 31;
    int t0 = tc * 8;

    // stage 10 halo planes (t0-1 .. t0+8), 10x34 each, zero-padded
    for (int i = tid; i < 3400; i += 256) {
        int j = i / 340, pos = i - j*340;
        int py = pos / 34, px = pos - py*34;
        int t = t0 - 1 + j;
        int gy = ty0 - 1 + py, gx = tx0 - 1 + px;
        float v = 0.f;
        if (t >= 0 && t < TT && gy >= 0 && gy < TH && gx >= 0 && gx < TW)
            v = in[((long)(b*TT + t))*THW + gy*TW + gx];
        pl[j*(10*LSK) + py*LSK + px] = v;
    }
    __syncthreads();

    int c0 = chalf * 16;
    long gbase = chalf ? GF_OFF_US : 0L;
    int hwt = tile*256 + lyk*32 + lxk;       // TILED in-plane offset (contiguous per tile)

    float s[16], q[16];
    #pragma unroll
    for (int c = 0; c < 16; ++c) { s[c] = 0.f; q[c] = 0.f; }

    #pragma unroll 1
    for (int jj = 0; jj < 2; ++jj) {
        int tbase = t0 + 4*jj;
        int nv = TT - tbase; if (nv > 4) nv = 4;   // 4 always, except 3 at tc=3,jj=1

        // load 6 tap planes (covers outputs tbase..tbase+3)
        float tap[54];
        #pragma unroll
        for (int lp = 0; lp < 6; ++lp)
            #pragma unroll
            for (int ky = 0; ky < 3; ++ky)
                #pragma unroll
                for (int kx = 0; kx < 3; ++kx)
                    tap[lp*9 + ky*3 + kx] =
                        pl[(4*jj + lp)*(10*LSK) + (lyk+ky)*LSK + (lxk+kx)];
        // Pin taps in VGPRs: prevents LDS-remat inside the channel loop.
        #pragma unroll
        for (int i = 0; i < 54; ++i)
            asm volatile("" : "+v"(tap[i]));

        #pragma unroll
        for (int c = 0; c < 16; ++c) {
            const float* w = wg + (c0 + c)*27;
            float v0 = 0.f, v1 = 0.f, v2 = 0.f, v3 = 0.f;
            #pragma unroll
            for (int kt = 0; kt < 3; ++kt)
                #pragma unroll
                for (int kk = 0; kk < 9; ++kk) {
                    float wv = w[kt*9 + kk];
                    v0 = fmaf(wv, tap[(0+kt)*9 + kk], v0);
                    v1 = fmaf(wv, tap[(1+kt)*9 + kk], v1);
                    v2 = fmaf(wv, tap[(2+kt)*9 + kk], v2);
                    v3 = fmaf(wv, tap[(3+kt)*9 + kk], v3);
                }
            long cb = gbase + ((long)((b*HCN + c)*TT + tbase))*THW + hwt;
            s[c] += v0; q[c] += v0*v0; gout[cb]           = f2bf(v0);
            if (nv > 1) { s[c] += v1; q[c] += v1*v1; gout[cb +   (long)THW] = f2bf(v1); }
            if (nv > 2) { s[c] += v2; q[c] += v2*v2; gout[cb + 2L*(long)THW] = f2bf(v2); }
            if (nv > 3) { s[c] += v3; q[c] += v3*v3; gout[cb + 3L*(long)THW] = f2bf(v3); }
        }
    }

    // block reduce 16 channels x (sum, sumsq)
    int lane = tid & 63, wid = tid >> 6;
    #pragma unroll
    for (int c = 0; c < 16; ++c) {
        float ss = s[c], qq = q[c];
        #pragma unroll
        for (int off = 32; off > 0; off >>= 1) {
            ss += __shfl_down(ss, off, 64);
            qq += __shfl_down(qq, off, 64);
        }
        if (lane == 0) { redS[wid][c] = ss; redQ[wid][c] = qq; }
    }
    __syncthreads();
    if (tid < 16) {
        int ch = c0 + tid;
        float ss = redS[0][tid] + redS[1][tid] + redS[2][tid] + redS[3][tid];
        float qq = redQ[0][tid] + redQ[1][tid] + redQ[2][tid] + redQ[3][tid];
        atomicAdd(&stats[ch], ss);
        atomicAdd(&stats[32 + ch], qq);
    }
}

// ---------- kernel 3: BN + act + scan, TILED, ushort4/thread (frozen) ----------
// grid: (25, 16 ch, 2 b), block 256; each thread: 4 px, scans t
__global__ __launch_bounds__(256)
void k3_scan(ushort4* gz, const ushort4* gf,
             const float* __restrict__ stats,
             const float* __restrict__ gamma, const float* __restrict__ beta,
             const int* __restrict__ rev_p) {
    int c = blockIdx.y, b = blockIdx.z;
    int p4 = blockIdx.x * blockDim.x + threadIdx.x;    // ushort4 index in plane (tiled)
    float n = (float)NPER;
    float mz = stats[c] / n,        vz = stats[32 + c] / n - mz*mz;
    float az = gamma[c] * rsqrtf(vz + 1e-5f);
    float bz = beta[c] - mz * az;
    float mf = stats[16 + c] / n,   vf = stats[48 + c] / n - mf*mf;
    float af = gamma[16 + c] * rsqrtf(vf + 1e-5f);
    float bf = beta[16 + c] - mf * af;
    int rev = rev_p[0];

    long zb = ((long)((b*HCN + c)*TT)) * (THW/4) + p4;

    float h0 = 0.f, h1 = 0.f, h2 = 0.f, h3 = 0.f;

#define K3_STEP(t)                                                        \
    {                                                                     \
        long o = zb + (long)(t) * (THW/4);                                \
        ushort4 zu = gz[o];                                               \
        ushort4 fu = gf[o];                                               \
        float z0 = tanhf_(fmaf(az, b2f(zu.x), bz));                       \
        float z1 = tanhf_(fmaf(az, b2f(zu.y), bz));                       \
        float z2 = tanhf_(fmaf(az, b2f(zu.z), bz));                       \
        float z3 = tanhf_(fmaf(az, b2f(zu.w), bz));                       \
        float f0 = sigmoidf_(fmaf(af, b2f(fu.x), bf));                    \
        float f1 = sigmoidf_(fmaf(af, b2f(fu.y), bf));                    \
        float f2 = sigmoidf_(fmaf(af, b2f(fu.z), bf));                    \
        float f3 = sigmoidf_(fmaf(af, b2f(fu.w), bf));                    \
        h0 = f0*h0 + (1.f - f0)*z0;                                       \
        h1 = f1*h1 + (1.f - f1)*z1;                                       \
        h2 = f2*h2 + (1.f - f2)*z2;                                       \
        h3 = f3*h3 + (1.f - f3)*z3;                                       \
        ushort4 hu;                                                       \
        hu.x = f2bf(h0); hu.y = f2bf(h1); hu.z = f2bf(h2); hu.w = f2bf(h3); \
        gz[o] = hu;                                                       \
    }

    if (!rev) {
        for (int t = 0; t < TT; ++t) K3_STEP(t)
    } else {
        for (int t = TT - 1; t >= 0; --t) K3_STEP(t)
    }
#undef K3_STEP
}

// ---------- kernel 4: conv2 OR conv3 per block, XCD swizzle, tiled h reads ----------
// R23: batched per-t load block. Per t, issue ALL 72 loads (8 ch x 9) into a
// static E[8][3][3] register file (asm-pinned so the scheduler cannot sink
// loads back toward uses), then compute 8 channel-planes straight-line.
// vs R22: one waitcnt per t instead of 8, 72 outstanding loads/wave instead
// of 9, zero rotation movs (720/chunk eliminated), batched pointer math.
// Store/rotate logic byte-equivalent to R22 -> bitwise-identical results.
// grid: 800 linear (16 chunks x 50 tiles), block 256
#define K4TCH 8
__global__ __launch_bounds__(256)
void k4_conv23(const unsigned short* __restrict__ hb, const float* __restrict__ wsc,
               const float* __restrict__ wsh, unsigned short* __restrict__ c2,
               unsigned short* __restrict__ c3, float* __restrict__ stats2) {
    __shared__ float red[2][4];

    // decode XCD-chunked flat id (16 chunks of 50 tiles)
    int nfl  = blockIdx.x;
    int xcd  = nfl & 7;
    int slot = nfl >> 3;           // 0..99
    int cc_  = slot / 50;          // chunk group 0..1
    int tile = slot - cc_*50;      // 0..49
    int c_   = cc_*8 + xcd;        // chunk 0..15
    int cv   = c_ & 1;
    int tch  = (c_ >> 1) & 3;
    int b    = c_ >> 3;

    int t0 = tch * K4TCH;
    int t1 = min(t0 + K4TCH - 1, TT - 1);
    int ty0 = (tile / 5) * 16, tx0 = (tile % 5) * 32;
    int tid = threadIdx.x;
    int k   = tid & 15;            // x-pair index
    int ly  = tid >> 4;            // row 0..15
    int y = ty0 + ly, x0 = tx0 + 2*k;

    const float* wv = cv ? wsh : wsc;
    unsigned short* co = cv ? c3 : c2;
    int cbase = cv ? 8 : 0;

    int ts = max(t0 - 1, 0), te = min(t1 + 1, TT - 1);

    // per-thread constants: 9 tiled uint offsets + per-row masks
    int xm2 = max(x0 - 2, 0);
    int xp2 = min(x0 + 2, TW - 2);
    unsigned int mL = (x0 == 0)      ? 0u : 0xffff0000u;
    unsigned int mR = (x0 == TW - 2) ? 0u : 0x0000ffffu;
    int off_[3][3];
    unsigned int mHi0[3], mRow[3], mLo2[3];
    #pragma unroll
    for (int ky = 0; ky < 3; ++ky) {
        int gy = y - 1 + ky;
        bool ok = (gy >= 0 && gy < TH);
        int gyc = min(max(gy, 0), TH - 1);
        off_[ky][0] = uoff_tiled(gyc, xm2);
        off_[ky][1] = uoff_tiled(gyc, x0);
        off_[ky][2] = uoff_tiled(gyc, xp2);
        unsigned int rm = ok ? 0xffffffffu : 0u;
        mHi0[ky] = rm & mL;
        mRow[ky] = rm;
        mLo2[ky] = rm & mR;
    }

    float aPx=0.f,aPy=0.f,aCx=0.f,aCy=0.f,aNx=0.f,aNy=0.f;
    float sl = 0.f, ql = 0.f;

    #pragma unroll 1
    for (int tl = ts; tl <= te; ++tl) {
        // ---- batched load block: 8 channels x 9 loads into registers ----
        unsigned int E[8][3][3];
        #pragma unroll
        for (int cc = 0; cc < 8; ++cc) {
            const unsigned int* pp = (const unsigned int*)(hb + ((long)((b*HCN + cbase + cc)*TT + tl))*THW);
            #pragma unroll
            for (int ky = 0; ky < 3; ++ky) {
                E[cc][ky][0] = pp[off_[ky][0]];
                E[cc][ky][1] = pp[off_[ky][1]];
                E[cc][ky][2] = pp[off_[ky][2]];
            }
        }
        // pin: force all 72 loads to be issued (and live) before any compute
        #pragma unroll
        for (int cc = 0; cc < 8; ++cc)
            #pragma unroll
            for (int ky = 0; ky < 3; ++ky)
                #pragma unroll
                for (int j = 0; j < 3; ++j)
                    asm volatile("" : "+v"(E[cc][ky][j]));

        // ---- compute 8 channel-planes straight-line ----
        #pragma unroll
        for (int cc = 0; cc < 8; ++cc) {
            const float* w = wv + cc*27;
            #pragma unroll
            for (int ky = 0; ky < 3; ++ky) {
                unsigned int u0 = E[cc][ky][0];
                unsigned int u1 = E[cc][ky][1];
                unsigned int u2 = E[cc][ky][2];
                float v1 = __uint_as_float(u0 & mHi0[ky]);         // x0-1
                unsigned int tm = u1 & mRow[ky];
                float v2 = __uint_as_float(tm << 16);              // x0
                float v3 = __uint_as_float(tm & 0xffff0000u);      // x0+1
                float v4 = __uint_as_float((u2 & mLo2[ky]) << 16); // x0+2
                float wN0 = w[ky*3+0],   wN1 = w[ky*3+1],   wN2 = w[ky*3+2];
                float wC0 = w[9+ky*3+0], wC1 = w[9+ky*3+1], wC2 = w[9+ky*3+2];
                float wP0 = w[18+ky*3+0],wP1 = w[18+ky*3+1],wP2 = w[18+ky*3+2];
                aNx = fmaf(wN0,v1,aNx); aNx = fmaf(wN1,v2,aNx); aNx = fmaf(wN2,v3,aNx);
                aNy = fmaf(wN0,v2,aNy); aNy = fmaf(wN1,v3,aNy); aNy = fmaf(wN2,v4,aNy);
                aCx = fmaf(wC0,v1,aCx); aCx = fmaf(wC1,v2,aCx); aCx = fmaf(wC2,v3,aCx);
                aCy = fmaf(wC0,v2,aCy); aCy = fmaf(wC1,v3,aCy); aCy = fmaf(wC2,v4,aCy);
                aPx = fmaf(wP0,v1,aPx); aPx = fmaf(wP1,v2,aPx); aPx = fmaf(wP2,v3,aPx);
                aPy = fmaf(wP0,v2,aPy); aPy = fmaf(wP1,v3,aPy); aPy = fmaf(wP2,v4,aPy);
            }
        }

        // ---- per-t store + rotation (identical logic to R22's cc==7 path) ----
        int t_out = tl - 1;
        if (t_out >= t0 && t_out <= t1) {
            long oidx = ((long)(b*TT + t_out)) * THW + (long)y*TW + x0;
            ushort2 o; o.x = f2bf(aPx); o.y = f2bf(aPy);
            *(ushort2*)&co[oidx] = o;
            sl += aPx + aPy; ql += aPx*aPx + aPy*aPy;
        }
        aPx=aCx; aCx=aNx; aNx=0.f;  aPy=aCy; aCy=aNy; aNy=0.f;
    }
    if (t1 == TT - 1) {
        long oidx = ((long)(b*TT + (TT - 1))) * THW + (long)y*TW + x0;
        ushort2 o; o.x = f2bf(aPx); o.y = f2bf(aPy);
        *(ushort2*)&co[oidx] = o;
        sl += aPx + aPy; ql += aPx*aPx + aPy*aPy;
    }

    #pragma unroll
    for (int off = 32; off > 0; off >>= 1) {
        sl += __shfl_down(sl, off, 64);
        ql += __shfl_down(ql, off, 64);
    }
    int lane = tid & 63, wid = tid >> 6;
    if (lane == 0) { red[0][wid] = sl; red[1][wid] = ql; }
    __syncthreads();
    if (tid == 0) {
        atomicAdd(&stats2[2*cv],     red[0][0] + red[0][1] + red[0][2] + red[0][3]);
        atomicAdd(&stats2[2*cv + 1], red[1][0] + red[1][1] + red[1][2] + red[1][3]);
    }
}

// ---------- kernel 6: epilogue (frozen) ----------
__global__ __launch_bounds__(256)
void k6_final(const ushort4* __restrict__ c2, const ushort4* __restrict__ c3,
              const float* __restrict__ stats2,
              const float* __restrict__ gs, const float* __restrict__ bs,
              const float* __restrict__ gt, const float* __restrict__ bt,
              float4* __restrict__ out) {
    int i = blockIdx.x * blockDim.x + threadIdx.x;
    if (i < NPER/4) {
        float n = (float)NPER;
        float m2 = stats2[0] / n, v2v = stats2[1] / n - m2*m2;
        float a2 = gs[0] * rsqrtf(v2v + 1e-5f);
        float b2 = bs[0] - m2*a2;
        float m3 = stats2[2] / n, v3v = stats2[3] / n - m3*m3;
        float a3 = gt[0] * rsqrtf(v3v + 1e-5f);
        float b3 = bt[0] - m3*a3;

        ushort4 u2 = c2[i], u3 = c3[i];
        float4 sc, sh;
        sc.x = sigmoidf_(fmaf(a2, b2f(u2.x), b2) + 2.f) + 1e-4f;
        sc.y = sigmoidf_(fmaf(a2, b2f(u2.y), b2) + 2.f) + 1e-4f;
        sc.z = sigmoidf_(fmaf(a2, b2f(u2.z), b2) + 2.f) + 1e-4f;
        sc.w = sigmoidf_(fmaf(a2, b2f(u2.w), b2) + 2.f) + 1e-4f;
        sh.x = fmaf(a3, b2f(u3.x), b3);
        sh.y = fmaf(a3, b2f(u3.y), b3);
        sh.z = fmaf(a3, b2f(u3.z), b3);
        sh.w = fmaf(a3, b2f(u3.w), b3);
        out[i] = sc;
        out[NPER/4 + i] = sh;
    }
}

// ---------- launch ----------
extern "C" void kernel_launch(void* const* d_in, const int* in_sizes, int n_in,
                              void* d_out, int out_size, void* d_ws, size_t ws_size,
                              hipStream_t stream) {
    const float* in          = (const float*)d_in[0];
    const float* w_gate      = (const float*)d_in[1];
    const float* gamma_gate  = (const float*)d_in[2];
    const float* beta_gate   = (const float*)d_in[3];
    const float* w_scale     = (const float*)d_in[4];
    const float* gamma_scale = (const float*)d_in[5];
    const float* beta_scale  = (const float*)d_in[6];
    const float* w_shift     = (const float*)d_in[7];
    const float* gamma_shift = (const float*)d_in[8];
    const float* beta_shift  = (const float*)d_in[9];
    const int*   rev         = (const int*)d_in[10];

    unsigned short* g   = (unsigned short*)d_ws;                    // gates bf16 TILED (z then f); z-half becomes h (TILED)
    unsigned short* c2b = (unsigned short*)((char*)d_ws + C2_BYTE); // bf16 standard, aliases dead f-gates
    unsigned short* c3b = c2b + NPER;
    float* st  = (float*)((char*)d_ws + STATS_BYTE);
    float* s1  = st;            // 64: sum[32], sumsq[32]
    float* s2  = st + 64;       // 4: sum2,sumsq2,sum3,sumsq3
    float* out = (float*)d_out;

    hipMemsetAsync(st, 0, 68 * sizeof(float), stream);

    k1_gates_stats<<<dim3(8, 100, TB), 256, 0, stream>>>(in, w_gate, g, s1);
    k3_scan<<<dim3(25, HCN, TB), 256, 0, stream>>>((ushort4*)g,
                                                   (const ushort4*)(g + GF_OFF_US),
                                                   s1, gamma_gate, beta_gate, rev);
    k4_conv23<<<800, 256, 0, stream>>>(g, w_scale, w_shift, c2b, c3b, s2);
    k6_final<<<(NPER/4 + 255)/256, 256, 0, stream>>>((const ushort4*)c2b, (const ushort4*)c3b,
                                                     s2, gamma_scale, beta_scale,
                                                     gamma_shift, beta_shift, (float4*)out);
}

// Round 12
// 227.142 us; speedup vs baseline: 1.0582x; 1.0582x over previous
//
#include <hip/hip_runtime.h>
#include <math.h>

// Problem constants
#define TB 2
#define TT 31
#define TH 160
#define TW 160
#define THW (TH*TW)            // 25600
#define NPER (TB*TT*THW)       // 1,587,200
#define HCN 16
#define LSK 40                 // k1 LDS row stride

// Workspace layout (bytes). gates bf16: z-half [0,50.79MB), f-half [50.79,101.58MB).
// After k3, z-half is overwritten in-place with h (bf16). c2/c3 (bf16) alias the
// (dead) f-half. Stats at the end. Total ~101.6MB.
// R24: reverted to the measured-best R19/_7 config (236.1us) — standard layout
// everywhere; the R20-R23 tiled chain proved k4 is fetch-insensitive (142->30MB,
// no dur change) and netted +1..+4us vs this base. Only K4TCH=8 (the one k4
// lever with an independent within-era win, R21->R22 -4us) is ported over.
#define GF_OFF_US  25395200L    // ushort offset of f-gates (2*16*31*25600)
#define C2_BYTE    50790400L    // byte offset of c2 bf16 (aliases f-gates, dead by then)
#define STATS_BYTE 101580800L

__device__ __forceinline__ float sigmoidf_(float x) {
    return __builtin_amdgcn_rcpf(1.f + __expf(-x));
}
__device__ __forceinline__ float tanhf_(float x) {
    return 2.f * __builtin_amdgcn_rcpf(1.f + __expf(-2.f * x)) - 1.f;
}
__device__ __forceinline__ unsigned short f2bf(float v) {
    unsigned int b = __float_as_uint(v);
    unsigned int r = (b + 0x7FFFu + ((b >> 16) & 1u)) >> 16;   // RNE
    return (unsigned short)r;
}
__device__ __forceinline__ float b2f(unsigned short u) {
    return __uint_as_float(((unsigned int)u) << 16);
}

// ---------- kernel 1: conv1 via LDS staging — R19 4-t-per-group (frozen from _7).
// 54 taps cover 4 t-outputs; 27 weight loads feed 108 FMAs; 4 independent
// accumulator chains per weight. Taps asm-pinned against LDS remat.
// grid: (8 = chalf*4 + tchunk, 100 tiles 32x8, 2 b), block 256
__global__ __launch_bounds__(256)
void k1_gates_stats(const float* __restrict__ in, const float* __restrict__ wg,
                    unsigned short* __restrict__ gout, float* __restrict__ stats) {
    __shared__ float pl[10*10*LSK];          // 10 t-planes, 10 rows x 40 (34 used)
    __shared__ float redS[4][16], redQ[4][16];

    int bx = blockIdx.x;
    int tc = bx & 3, chalf = bx >> 2;
    int tile = blockIdx.y, b = blockIdx.z;
    int ty0 = (tile / 5) * 8, tx0 = (tile % 5) * 32;
    int tid = threadIdx.x;
    int lyk = tid >> 5, lxk = tid & 31;
    int t0 = tc * 8;

    // stage 10 halo planes (t0-1 .. t0+8), 10x34 each, zero-padded
    for (int i = tid; i < 3400; i += 256) {
        int j = i / 340, pos = i - j*340;
        int py = pos / 34, px = pos - py*34;
        int t = t0 - 1 + j;
        int gy = ty0 - 1 + py, gx = tx0 - 1 + px;
        float v = 0.f;
        if (t >= 0 && t < TT && gy >= 0 && gy < TH && gx >= 0 && gx < TW)
            v = in[((long)(b*TT + t))*THW + gy*TW + gx];
        pl[j*(10*LSK) + py*LSK + px] = v;
    }
    __syncthreads();

    int c0 = chalf * 16;
    long gbase = chalf ? GF_OFF_US : 0L;
    int y = ty0 + lyk, x = tx0 + lxk;
    int hw = y*TW + x;

    float s[16], q[16];
    #pragma unroll
    for (int c = 0; c < 16; ++c) { s[c] = 0.f; q[c] = 0.f; }

    #pragma unroll 1
    for (int jj = 0; jj < 2; ++jj) {
        int tbase = t0 + 4*jj;
        int nv = TT - tbase; if (nv > 4) nv = 4;   // 4 always, except 3 at tc=3,jj=1

        // load 6 tap planes (covers outputs tbase..tbase+3)
        float tap[54];
        #pragma unroll
        for (int lp = 0; lp < 6; ++lp)
            #pragma unroll
            for (int ky = 0; ky < 3; ++ky)
                #pragma unroll
                for (int kx = 0; kx < 3; ++kx)
                    tap[lp*9 + ky*3 + kx] =
                        pl[(4*jj + lp)*(10*LSK) + (lyk+ky)*LSK + (lxk+kx)];
        // Pin taps in VGPRs: prevents LDS-remat inside the channel loop.
        #pragma unroll
        for (int i = 0; i < 54; ++i)
            asm volatile("" : "+v"(tap[i]));

        #pragma unroll
        for (int c = 0; c < 16; ++c) {
            const float* w = wg + (c0 + c)*27;
            float v0 = 0.f, v1 = 0.f, v2 = 0.f, v3 = 0.f;
            #pragma unroll
            for (int kt = 0; kt < 3; ++kt)
                #pragma unroll
                for (int kk = 0; kk < 9; ++kk) {
                    float wv = w[kt*9 + kk];
                    v0 = fmaf(wv, tap[(0+kt)*9 + kk], v0);
                    v1 = fmaf(wv, tap[(1+kt)*9 + kk], v1);
                    v2 = fmaf(wv, tap[(2+kt)*9 + kk], v2);
                    v3 = fmaf(wv, tap[(3+kt)*9 + kk], v3);
                }
            long cb = gbase + ((long)((b*HCN + c)*TT + tbase))*THW + hw;
            s[c] += v0; q[c] += v0*v0; gout[cb]           = f2bf(v0);
            if (nv > 1) { s[c] += v1; q[c] += v1*v1; gout[cb +   (long)THW] = f2bf(v1); }
            if (nv > 2) { s[c] += v2; q[c] += v2*v2; gout[cb + 2L*(long)THW] = f2bf(v2); }
            if (nv > 3) { s[c] += v3; q[c] += v3*v3; gout[cb + 3L*(long)THW] = f2bf(v3); }
        }
    }

    // block reduce 16 channels x (sum, sumsq)
    int lane = tid & 63, wid = tid >> 6;
    #pragma unroll
    for (int c = 0; c < 16; ++c) {
        float ss = s[c], qq = q[c];
        #pragma unroll
        for (int off = 32; off > 0; off >>= 1) {
            ss += __shfl_down(ss, off, 64);
            qq += __shfl_down(qq, off, 64);
        }
        if (lane == 0) { redS[wid][c] = ss; redQ[wid][c] = qq; }
    }
    __syncthreads();
    if (tid < 16) {
        int ch = c0 + tid;
        float ss = redS[0][tid] + redS[1][tid] + redS[2][tid] + redS[3][tid];
        float qq = redQ[0][tid] + redQ[1][tid] + redQ[2][tid] + redQ[3][tid];
        atomicAdd(&stats[ch], ss);
        atomicAdd(&stats[32 + ch], qq);
    }
}

// ---------- kernel 3: pointwise BN + act + scan (R18/_7 form, frozen) ----------
// Three __restrict__ pointers (h == z region; each address read-then-written
// by the same thread only). grid: (25, 16 ch, 2 b), block 256
__global__ __launch_bounds__(256)
void k3_scan(const ushort4* __restrict__ z4, const ushort4* __restrict__ f4,
             ushort4* __restrict__ h4,
             const float* __restrict__ stats,
             const float* __restrict__ gamma, const float* __restrict__ beta,
             const int* __restrict__ rev_p) {
    int c = blockIdx.y, b = blockIdx.z;
    int p4 = blockIdx.x * blockDim.x + threadIdx.x;    // ushort4 index in plane
    float n = (float)NPER;
    float mz = stats[c] / n,        vz = stats[32 + c] / n - mz*mz;
    float az = gamma[c] * rsqrtf(vz + 1e-5f);
    float bz = beta[c] - mz * az;
    float mf = stats[16 + c] / n,   vf = stats[48 + c] / n - mf*mf;
    float af = gamma[16 + c] * rsqrtf(vf + 1e-5f);
    float bf = beta[16 + c] - mf * af;
    int rev = rev_p[0];

    long zb = ((long)((b*HCN + c)*TT)) * (THW/4) + p4;

    float h0 = 0.f, h1 = 0.f, h2 = 0.f, h3 = 0.f;

#define K3_STEP(t)                                                        \
    {                                                                     \
        long o = zb + (long)(t) * (THW/4);                                \
        ushort4 zu = z4[o];                                               \
        ushort4 fu = f4[o];                                               \
        float z0 = tanhf_(fmaf(az, b2f(zu.x), bz));                       \
        float z1 = tanhf_(fmaf(az, b2f(zu.y), bz));                       \
        float z2 = tanhf_(fmaf(az, b2f(zu.z), bz));                       \
        float z3 = tanhf_(fmaf(az, b2f(zu.w), bz));                       \
        float f0 = sigmoidf_(fmaf(af, b2f(fu.x), bf));                    \
        float f1 = sigmoidf_(fmaf(af, b2f(fu.y), bf));                    \
        float f2 = sigmoidf_(fmaf(af, b2f(fu.z), bf));                    \
        float f3 = sigmoidf_(fmaf(af, b2f(fu.w), bf));                    \
        h0 = f0*h0 + (1.f - f0)*z0;                                       \
        h1 = f1*h1 + (1.f - f1)*z1;                                       \
        h2 = f2*h2 + (1.f - f2)*z2;                                       \
        h3 = f3*h3 + (1.f - f3)*z3;                                       \
        ushort4 hu;                                                       \
        hu.x = f2bf(h0); hu.y = f2bf(h1); hu.z = f2bf(h2); hu.w = f2bf(h3); \
        h4[o] = hu;                                                       \
    }

    if (!rev) {
        for (int t = 0; t < TT; ++t) K3_STEP(t)
    } else {
        for (int t = TT - 1; t >= 0; --t) K3_STEP(t)
    }
#undef K3_STEP
}

// ---------- kernel 4: conv2 OR conv3 per block, XCD-locality swizzle ----------
// R18/_7 body (standard layout, rowbase+column loads, cross-plane prefetch
// depth 1) with R24's single change: K4TCH 4 -> 8. t-halo amortization:
// 10 halo planes per 8 outputs (1.25/output) vs 6 per 4 (1.5/output) —
// the only k4 lever that measured positive in isolation (R21->R22, -4us).
// grid: 800 linear (16 chunks x 50 tiles), block 256
#define K4TCH 8
__global__ __launch_bounds__(256)
void k4_conv23(const unsigned short* __restrict__ hb, const float* __restrict__ wsc,
               const float* __restrict__ wsh, unsigned short* __restrict__ c2,
               unsigned short* __restrict__ c3, float* __restrict__ stats2) {
    __shared__ float red[2][4];

    // decode XCD-chunked flat id (16 chunks of 50 tiles)
    int nfl  = blockIdx.x;
    int xcd  = nfl & 7;
    int slot = nfl >> 3;           // 0..99
    int cc_  = slot / 50;          // chunk group 0..1
    int tile = slot - cc_*50;      // 0..49
    int c_   = cc_*8 + xcd;        // chunk 0..15
    int cv   = c_ & 1;
    int tch  = (c_ >> 1) & 3;
    int b    = c_ >> 3;

    int t0 = tch * K4TCH;
    int t1 = min(t0 + K4TCH - 1, TT - 1);
    int ty0 = (tile / 5) * 16, tx0 = (tile % 5) * 32;
    int tid = threadIdx.x;
    int k   = tid & 15;            // x-pair index
    int ly  = tid >> 4;            // row 0..15
    int y = ty0 + ly, x0 = tx0 + 2*k;

    const float* wv = cv ? wsh : wsc;
    unsigned short* co = cv ? c3 : c2;
    int cbase = cv ? 8 : 0;

    int ts = max(t0 - 1, 0), te = min(t1 + 1, TT - 1);
    int nplanes = (te - ts + 1) * 8;

    // per-thread constants: uint element offsets within a plane, per-row masks
    int e0 = max(x0 - 2, 0) >> 1;
    int e1 = x0 >> 1;
    int e2 = min(x0 + 2, TW - 2) >> 1;
    unsigned int mL = (x0 == 0)      ? 0u : 0xffff0000u;
    unsigned int mR = (x0 == TW - 2) ? 0u : 0x0000ffffu;
    int rowb[3];
    unsigned int mHi0[3], mRow[3], mLo2[3];
    #pragma unroll
    for (int ky = 0; ky < 3; ++ky) {
        int gy = y - 1 + ky;
        bool ok = (gy >= 0 && gy < TH);
        int gyc = min(max(gy, 0), TH - 1);
        rowb[ky] = gyc * (TW/2);
        unsigned int rm = ok ? 0xffffffffu : 0u;
        mHi0[ky] = rm & mL;
        mRow[ky] = rm;
        mLo2[ky] = rm & mR;
    }

    float aPx=0.f,aPy=0.f,aCx=0.f,aCy=0.f,aNx=0.f,aNy=0.f;
    float sl = 0.f, ql = 0.f;

    // preload plane 0 into u[][]
    unsigned int u[3][3];
    {
        const unsigned int* pp0 = (const unsigned int*)(hb + ((long)((b*HCN + cbase + 0)*TT + ts))*THW);
        #pragma unroll
        for (int ky = 0; ky < 3; ++ky) {
            u[ky][0] = pp0[rowb[ky] + e0];
            u[ky][1] = pp0[rowb[ky] + e1];
            u[ky][2] = pp0[rowb[ky] + e2];
        }
    }

    #pragma unroll 1
    for (int p = 0; p < nplanes; ++p) {
        int cc = p & 7, t_in = ts + (p >> 3);

        // prefetch plane p+1 (clamped; last-iter redundant load is harmless)
        int pn = (p + 1 < nplanes) ? (p + 1) : p;
        int ccn = pn & 7, t_inn = ts + (pn >> 3);
        const unsigned int* ppn = (const unsigned int*)(hb + ((long)((b*HCN + cbase + ccn)*TT + t_inn))*THW);
        unsigned int un[3][3];
        #pragma unroll
        for (int ky = 0; ky < 3; ++ky) {
            un[ky][0] = ppn[rowb[ky] + e0];
            un[ky][1] = ppn[rowb[ky] + e1];
            un[ky][2] = ppn[rowb[ky] + e2];
        }

        const float* w = wv + cc*27;
        #pragma unroll
        for (int ky = 0; ky < 3; ++ky) {
            unsigned int u0 = u[ky][0];
            unsigned int u1 = u[ky][1];
            unsigned int u2 = u[ky][2];
            float v1 = __uint_as_float(u0 & mHi0[ky]);         // x0-1
            unsigned int tm = u1 & mRow[ky];
            float v2 = __uint_as_float(tm << 16);              // x0
            float v3 = __uint_as_float(tm & 0xffff0000u);      // x0+1
            float v4 = __uint_as_float((u2 & mLo2[ky]) << 16); // x0+2
            float wN0 = w[ky*3+0],   wN1 = w[ky*3+1],   wN2 = w[ky*3+2];
            float wC0 = w[9+ky*3+0], wC1 = w[9+ky*3+1], wC2 = w[9+ky*3+2];
            float wP0 = w[18+ky*3+0],wP1 = w[18+ky*3+1],wP2 = w[18+ky*3+2];
            aNx = fmaf(wN0,v1,aNx); aNx = fmaf(wN1,v2,aNx); aNx = fmaf(wN2,v3,aNx);
            aNy = fmaf(wN0,v2,aNy); aNy = fmaf(wN1,v3,aNy); aNy = fmaf(wN2,v4,aNy);
            aCx = fmaf(wC0,v1,aCx); aCx = fmaf(wC1,v2,aCx); aCx = fmaf(wC2,v3,aCx);
            aCy = fmaf(wC0,v2,aCy); aCy = fmaf(wC1,v3,aCy); aCy = fmaf(wC2,v4,aCy);
            aPx = fmaf(wP0,v1,aPx); aPx = fmaf(wP1,v2,aPx); aPx = fmaf(wP2,v3,aPx);
            aPy = fmaf(wP0,v2,aPy); aPy = fmaf(wP1,v3,aPy); aPy = fmaf(wP2,v4,aPy);
        }

        if (cc == 7) {
            int t_out = t_in - 1;
            if (t_out >= t0 && t_out <= t1) {
                long oidx = ((long)(b*TT + t_out)) * THW + (long)y*TW + x0;
                ushort2 o; o.x = f2bf(aPx); o.y = f2bf(aPy);
                *(ushort2*)&co[oidx] = o;
                sl += aPx + aPy; ql += aPx*aPx + aPy*aPy;
            }
            aPx=aCx; aCx=aNx; aNx=0.f;  aPy=aCy; aCy=aNy; aNy=0.f;
        }

        #pragma unroll
        for (int ky = 0; ky < 3; ++ky) {
            u[ky][0] = un[ky][0];
            u[ky][1] = un[ky][1];
            u[ky][2] = un[ky][2];
        }
    }
    if (t1 == TT - 1) {
        long oidx = ((long)(b*TT + (TT - 1))) * THW + (long)y*TW + x0;
        ushort2 o; o.x = f2bf(aPx); o.y = f2bf(aPy);
        *(ushort2*)&co[oidx] = o;
        sl += aPx + aPy; ql += aPx*aPx + aPy*aPy;
    }

    #pragma unroll
    for (int off = 32; off > 0; off >>= 1) {
        sl += __shfl_down(sl, off, 64);
        ql += __shfl_down(ql, off, 64);
    }
    int lane = tid & 63, wid = tid >> 6;
    if (lane == 0) { red[0][wid] = sl; red[1][wid] = ql; }
    __syncthreads();
    if (tid == 0) {
        atomicAdd(&stats2[2*cv],     red[0][0] + red[0][1] + red[0][2] + red[0][3]);
        atomicAdd(&stats2[2*cv + 1], red[1][0] + red[1][1] + red[1][2] + red[1][3]);
    }
}

// ---------- kernel 6: epilogue (frozen) ----------
__global__ __launch_bounds__(256)
void k6_final(const ushort4* __restrict__ c2, const ushort4* __restrict__ c3,
              const float* __restrict__ stats2,
              const float* __restrict__ gs, const float* __restrict__ bs,
              const float* __restrict__ gt, const float* __restrict__ bt,
              float4* __restrict__ out) {
    int i = blockIdx.x * blockDim.x + threadIdx.x;
    if (i < NPER/4) {
        float n = (float)NPER;
        float m2 = stats2[0] / n, v2v = stats2[1] / n - m2*m2;
        float a2 = gs[0] * rsqrtf(v2v + 1e-5f);
        float b2 = bs[0] - m2*a2;
        float m3 = stats2[2] / n, v3v = stats2[3] / n - m3*m3;
        float a3 = gt[0] * rsqrtf(v3v + 1e-5f);
        float b3 = bt[0] - m3*a3;

        ushort4 u2 = c2[i], u3 = c3[i];
        float4 sc, sh;
        sc.x = sigmoidf_(fmaf(a2, b2f(u2.x), b2) + 2.f) + 1e-4f;
        sc.y = sigmoidf_(fmaf(a2, b2f(u2.y), b2) + 2.f) + 1e-4f;
        sc.z = sigmoidf_(fmaf(a2, b2f(u2.z), b2) + 2.f) + 1e-4f;
        sc.w = sigmoidf_(fmaf(a2, b2f(u2.w), b2) + 2.f) + 1e-4f;
        sh.x = fmaf(a3, b2f(u3.x), b3);
        sh.y = fmaf(a3, b2f(u3.y), b3);
        sh.z = fmaf(a3, b2f(u3.z), b3);
        sh.w = fmaf(a3, b2f(u3.w), b3);
        out[i] = sc;
        out[NPER/4 + i] = sh;
    }
}

// ---------- launch ----------
extern "C" void kernel_launch(void* const* d_in, const int* in_sizes, int n_in,
                              void* d_out, int out_size, void* d_ws, size_t ws_size,
                              hipStream_t stream) {
    const float* in          = (const float*)d_in[0];
    const float* w_gate      = (const float*)d_in[1];
    const float* gamma_gate  = (const float*)d_in[2];
    const float* beta_gate   = (const float*)d_in[3];
    const float* w_scale     = (const float*)d_in[4];
    const float* gamma_scale = (const float*)d_in[5];
    const float* beta_scale  = (const float*)d_in[6];
    const float* w_shift     = (const float*)d_in[7];
    const float* gamma_shift = (const float*)d_in[8];
    const float* beta_shift  = (const float*)d_in[9];
    const int*   rev         = (const int*)d_in[10];

    unsigned short* g   = (unsigned short*)d_ws;                    // gates bf16 (z then f); z-half becomes h
    unsigned short* c2b = (unsigned short*)((char*)d_ws + C2_BYTE); // bf16, aliases dead f-gates
    unsigned short* c3b = c2b + NPER;
    float* st  = (float*)((char*)d_ws + STATS_BYTE);
    float* s1  = st;            // 64: sum[32], sumsq[32]
    float* s2  = st + 64;       // 4: sum2,sumsq2,sum3,sumsq3
    float* out = (float*)d_out;

    hipMemsetAsync(st, 0, 68 * sizeof(float), stream);

    k1_gates_stats<<<dim3(8, 100, TB), 256, 0, stream>>>(in, w_gate, g, s1);
    k3_scan<<<dim3(25, HCN, TB), 256, 0, stream>>>((const ushort4*)g,
                                                   (const ushort4*)(g + GF_OFF_US),
                                                   (ushort4*)g,
                                                   s1, gamma_gate, beta_gate, rev);
    k4_conv23<<<800, 256, 0, stream>>>(g, w_scale, w_shift, c2b, c3b, s2);
    k6_final<<<(NPER/4 + 255)/256, 256, 0, stream>>>((const ushort4*)c2b, (const ushort4*)c3b,
                                                     s2, gamma_scale, beta_scale,
                                                     gamma_shift, beta_shift, (float4*)out);
}